// Round 1
// baseline (524.622 us; speedup 1.0000x reference)
//
#include <hip/hip_runtime.h>
#include <hip/hip_bf16.h>

#define NB  16
#define NN  16384
#define NC  256
#define NPP 128
#define NSS 16

// ---------------- weight transpose (one-shot, tiny) ----------------
__global__ __launch_bounds__(256) void transpose_kernel(
    const float* __restrict__ W1, const float* __restrict__ W2,
    const float* __restrict__ W3, const float* __restrict__ Wm,
    float* __restrict__ W1T, float* __restrict__ W2T,
    float* __restrict__ W3T, float* __restrict__ WmT) {
  int i = blockIdx.x * 256 + threadIdx.x;
  if (i < 128 * 259) { int o = i / 259, c = i - o * 259; W1T[c * 128 + o] = W1[i]; }
  if (i < 128 * 128) {
    int o = i >> 7, c = i & 127;
    W2T[c * 128 + o] = W2[i];
    W3T[c * 128 + o] = W3[i];
    WmT[c * 128 + o] = Wm[i];
    WmT[16384 + c * 128 + o] = Wm[16384 + i];
  }
}

// ---------------- FPS: one block per batch ----------------
// Bit-exact vs numpy: d = ((dx*dx + dy*dy) + dz*dz), each op rounded (no FMA),
// argmax tie-break = lowest index (numpy first-occurrence).
__global__ __launch_bounds__(1024) void fps_kernel(
    const float* __restrict__ xyz, int* __restrict__ fps_ws,
    float* __restrict__ centers, float* __restrict__ out_xyz,
    float* __restrict__ out_indf) {
  int b = blockIdx.x;
  const float* px = xyz + (size_t)b * (NN * 3);
  int t = threadIdx.x;
  float X[16], Y[16], Z[16], MD[16];
#pragma unroll
  for (int j = 0; j < 16; ++j) {
    int n = t + (j << 10);
    X[j] = px[n * 3 + 0];
    Y[j] = px[n * 3 + 1];
    Z[j] = px[n * 3 + 2];
    MD[j] = 1e10f;
  }
  __shared__ float sv[16];
  __shared__ int   si[16];
  __shared__ float sc[3];
  __shared__ int   swin;
  if (t == 0) {
    sc[0] = px[0]; sc[1] = px[1]; sc[2] = px[2];
    fps_ws[b * NPP] = 0;
    out_indf[b * NPP] = 0.0f;
    centers[(b * NPP) * 3 + 0] = px[0];
    centers[(b * NPP) * 3 + 1] = px[1];
    centers[(b * NPP) * 3 + 2] = px[2];
    out_xyz[(b * NPP) * 3 + 0] = px[0];
    out_xyz[(b * NPP) * 3 + 1] = px[1];
    out_xyz[(b * NPP) * 3 + 2] = px[2];
  }
  __syncthreads();
  for (int it = 1; it < NPP; ++it) {
    float cx = sc[0], cy = sc[1], cz = sc[2];
    float bv = -1.0f;
    int bi = 0;
#pragma unroll
    for (int j = 0; j < 16; ++j) {
      float dx = __fsub_rn(X[j], cx);
      float dy = __fsub_rn(Y[j], cy);
      float dz = __fsub_rn(Z[j], cz);
      float d  = __fadd_rn(__fadd_rn(__fmul_rn(dx, dx), __fmul_rn(dy, dy)),
                           __fmul_rn(dz, dz));
      float m = fminf(MD[j], d);
      MD[j] = m;
      if (m > bv) { bv = m; bi = t + (j << 10); }
    }
#pragma unroll
    for (int off = 1; off < 64; off <<= 1) {
      float ov = __shfl_xor(bv, off, 64);
      int   oi = __shfl_xor(bi, off, 64);
      if (ov > bv || (ov == bv && oi < bi)) { bv = ov; bi = oi; }
    }
    if ((t & 63) == 0) { sv[t >> 6] = bv; si[t >> 6] = bi; }
    __syncthreads();
    if (t < 64) {
      float v = (t < 16) ? sv[t] : -1.0f;
      int  ii = (t < 16) ? si[t] : 0;
#pragma unroll
      for (int off = 1; off < 16; off <<= 1) {
        float ov = __shfl_xor(v, off, 64);
        int   oi = __shfl_xor(ii, off, 64);
        if (ov > v || (ov == v && oi < ii)) { v = ov; ii = oi; }
      }
      if (t == 0) {
        swin = ii;
        fps_ws[b * NPP + it] = ii;
        out_indf[b * NPP + it] = (float)ii;
      }
    }
    __syncthreads();
    int win = swin;
    if (t == (win & 1023)) {
      int j = win >> 10;
      sc[0] = X[j]; sc[1] = Y[j]; sc[2] = Z[j];
      centers[(b * NPP + it) * 3 + 0] = X[j];
      centers[(b * NPP + it) * 3 + 1] = Y[j];
      centers[(b * NPP + it) * 3 + 2] = Z[j];
      out_xyz[(b * NPP + it) * 3 + 0] = X[j];
      out_xyz[(b * NPP + it) * 3 + 1] = Y[j];
      out_xyz[(b * NPP + it) * 3 + 2] = Z[j];
    }
    __syncthreads();
  }
}

// ---------------- ball query: one wave per (b, center) ----------------
__global__ __launch_bounds__(64) void ballq_kernel(
    const float* __restrict__ xyz, const float* __restrict__ centers,
    int* __restrict__ bidx) {
  int bs = blockIdx.x;  // b*128 + s
  int b = bs >> 7;
  int lane = threadIdx.x;
  const float* px = xyz + (size_t)b * (NN * 3);
  float cx = centers[bs * 3 + 0];
  float cy = centers[bs * 3 + 1];
  float cz = centers[bs * 3 + 2];
  __shared__ int coll[NSS];
  const float rr = 0.09f;  // f32(0.09): identical membership to f64 compare
  int have = 0;
  for (int c0 = 0; c0 < NN; c0 += 64) {
    int n = c0 + lane;
    float dx = __fsub_rn(px[n * 3 + 0], cx);
    float dy = __fsub_rn(px[n * 3 + 1], cy);
    float dz = __fsub_rn(px[n * 3 + 2], cz);
    float d2 = __fadd_rn(__fadd_rn(__fmul_rn(dx, dx), __fmul_rn(dy, dy)),
                         __fmul_rn(dz, dz));
    bool in = d2 < rr;
    unsigned long long m = __ballot(in);
    if (in) {
      int pos = have + __popcll(m & ((1ull << lane) - 1ull));
      if (pos < NSS) coll[pos] = n;
    }
    have += __popcll(m);
    if (have >= NSS) break;
  }
  __syncthreads();
  int first = coll[0];
  if (lane < NSS) bidx[bs * NSS + lane] = (lane < have) ? coll[lane] : first;
}

// ---------------- grouped MLP (3 layers + maxpool over NS) ----------------
__device__ __forceinline__ void layer_f(const float (*in)[20], int cin,
                                        const float* __restrict__ WT,
                                        const float* __restrict__ sc,
                                        const float* __restrict__ bi,
                                        int o2, int k0, float4& r0, float4& r1) {
  float a0[4] = {0.f, 0.f, 0.f, 0.f};
  float a1[4] = {0.f, 0.f, 0.f, 0.f};
  for (int c = 0; c < cin; ++c) {
    float2 w = *(const float2*)(WT + c * 128 + o2);
    float4 gv = *(const float4*)(&in[c][k0]);
    a0[0] = fmaf(w.x, gv.x, a0[0]);
    a0[1] = fmaf(w.x, gv.y, a0[1]);
    a0[2] = fmaf(w.x, gv.z, a0[2]);
    a0[3] = fmaf(w.x, gv.w, a0[3]);
    a1[0] = fmaf(w.y, gv.x, a1[0]);
    a1[1] = fmaf(w.y, gv.y, a1[1]);
    a1[2] = fmaf(w.y, gv.z, a1[2]);
    a1[3] = fmaf(w.y, gv.w, a1[3]);
  }
  float s0 = sc[o2], s1 = sc[o2 + 1], b0 = bi[o2], b1 = bi[o2 + 1];
  r0.x = fmaxf(fmaf(a0[0], s0, b0), 0.f);
  r0.y = fmaxf(fmaf(a0[1], s0, b0), 0.f);
  r0.z = fmaxf(fmaf(a0[2], s0, b0), 0.f);
  r0.w = fmaxf(fmaf(a0[3], s0, b0), 0.f);
  r1.x = fmaxf(fmaf(a1[0], s1, b1), 0.f);
  r1.y = fmaxf(fmaf(a1[1], s1, b1), 0.f);
  r1.z = fmaxf(fmaf(a1[2], s1, b1), 0.f);
  r1.w = fmaxf(fmaf(a1[3], s1, b1), 0.f);
}

__global__ __launch_bounds__(256) void mlp_kernel(
    const float* __restrict__ xyz, const float* __restrict__ feats,
    const float* __restrict__ centers, const int* __restrict__ bidx,
    const float* __restrict__ W1T, const float* __restrict__ W2T,
    const float* __restrict__ W3T, const float* __restrict__ sa_sc,
    const float* __restrict__ sa_bi, float* __restrict__ feat0) {
  int bs = blockIdx.x;
  int b = bs >> 7;
  int s = bs & 127;
  int tid = threadIdx.x;
  __shared__ float g[259][20];
  __shared__ float h1[128][20];
  __shared__ float h2[128][20];
  __shared__ int kidx[NSS];
  __shared__ float ctr[3];
  if (tid < NSS) kidx[tid] = bidx[bs * NSS + tid];
  if (tid < 3) ctr[tid] = centers[bs * 3 + tid];
  __syncthreads();
  const float* px = xyz + (size_t)b * (NN * 3);
  if (tid < NSS) {
    int n = kidx[tid];
    g[0][tid] = __fdiv_rn(__fsub_rn(px[n * 3 + 0], ctr[0]), 0.3f);
    g[1][tid] = __fdiv_rn(__fsub_rn(px[n * 3 + 1], ctr[1]), 0.3f);
    g[2][tid] = __fdiv_rn(__fsub_rn(px[n * 3 + 2], ctr[2]), 0.3f);
  }
  {
    const float* row = feats + ((size_t)b * NC + tid) * NN;
#pragma unroll
    for (int k = 0; k < NSS; ++k) g[3 + tid][k] = row[kidx[k]];
  }
  __syncthreads();
  int o2 = (tid & 63) * 2;
  int k0 = (tid >> 6) * 4;
  float4 r0, r1;
  layer_f(g, 259, W1T, sa_sc, sa_bi, o2, k0, r0, r1);
  *(float4*)&h1[o2][k0] = r0;
  *(float4*)&h1[o2 + 1][k0] = r1;
  __syncthreads();
  layer_f(h1, 128, W2T, sa_sc + 128, sa_bi + 128, o2, k0, r0, r1);
  *(float4*)&h2[o2][k0] = r0;
  *(float4*)&h2[o2 + 1][k0] = r1;
  __syncthreads();
  layer_f(h2, 128, W3T, sa_sc + 256, sa_bi + 256, o2, k0, r0, r1);
  float m0 = fmaxf(fmaxf(r0.x, r0.y), fmaxf(r0.z, r0.w));
  float m1 = fmaxf(fmaxf(r1.x, r1.y), fmaxf(r1.z, r1.w));
  int w = tid >> 6;
  h1[o2][w] = m0;
  h1[o2 + 1][w] = m1;
  __syncthreads();
  if (tid < 128) {
    float m = fmaxf(fmaxf(h1[tid][0], h1[tid][1]), fmaxf(h1[tid][2], h1[tid][3]));
    feat0[((size_t)b * 128 + tid) * 128 + s] = m;
  }
}

// ---------------- FC heads: (x@Wm + bm)*scale + bias, relu, x2 ----------------
__global__ __launch_bounds__(256) void head_kernel(
    const float* __restrict__ feat0, const float* __restrict__ WmT,
    const float* __restrict__ bm, const float* __restrict__ msc,
    const float* __restrict__ mbi, float* __restrict__ out_feat) {
  int blk = blockIdx.x;
  int b = blk >> 2;
  int sbase = (blk & 3) * 32;
  int tid = threadIdx.x;
  __shared__ float fa[128][36];
  __shared__ float fb[128][36];
  {
    int sj = tid & 31, c0 = tid >> 5;
    for (int c = c0; c < 128; c += 8)
      fa[c][sj] = feat0[((size_t)b * 128 + c) * 128 + sbase + sj];
  }
  __syncthreads();
  int o2 = (tid & 63) * 2, s0 = (tid >> 6) * 8;
  float a0[8], a1[8];
#pragma unroll
  for (int j = 0; j < 8; ++j) { a0[j] = 0.f; a1[j] = 0.f; }
  for (int c = 0; c < 128; ++c) {
    float2 w = *(const float2*)&WmT[c * 128 + o2];
    float4 f0 = *(const float4*)&fa[c][s0];
    float4 f1 = *(const float4*)&fa[c][s0 + 4];
    a0[0] = fmaf(w.x, f0.x, a0[0]); a0[1] = fmaf(w.x, f0.y, a0[1]);
    a0[2] = fmaf(w.x, f0.z, a0[2]); a0[3] = fmaf(w.x, f0.w, a0[3]);
    a0[4] = fmaf(w.x, f1.x, a0[4]); a0[5] = fmaf(w.x, f1.y, a0[5]);
    a0[6] = fmaf(w.x, f1.z, a0[6]); a0[7] = fmaf(w.x, f1.w, a0[7]);
    a1[0] = fmaf(w.y, f0.x, a1[0]); a1[1] = fmaf(w.y, f0.y, a1[1]);
    a1[2] = fmaf(w.y, f0.z, a1[2]); a1[3] = fmaf(w.y, f0.w, a1[3]);
    a1[4] = fmaf(w.y, f1.x, a1[4]); a1[5] = fmaf(w.y, f1.y, a1[5]);
    a1[6] = fmaf(w.y, f1.z, a1[6]); a1[7] = fmaf(w.y, f1.w, a1[7]);
  }
  {
    float c0 = bm[o2], c1 = bm[o2 + 1];
    float t0 = msc[o2], t1 = msc[o2 + 1];
    float q0 = mbi[o2], q1 = mbi[o2 + 1];
#pragma unroll
    for (int j = 0; j < 8; ++j) {
      fb[o2][s0 + j]     = fmaxf(fmaf(a0[j] + c0, t0, q0), 0.f);
      fb[o2 + 1][s0 + j] = fmaxf(fmaf(a1[j] + c1, t1, q1), 0.f);
    }
  }
  __syncthreads();
#pragma unroll
  for (int j = 0; j < 8; ++j) { a0[j] = 0.f; a1[j] = 0.f; }
  for (int c = 0; c < 128; ++c) {
    float2 w = *(const float2*)&WmT[16384 + c * 128 + o2];
    float4 f0 = *(const float4*)&fb[c][s0];
    float4 f1 = *(const float4*)&fb[c][s0 + 4];
    a0[0] = fmaf(w.x, f0.x, a0[0]); a0[1] = fmaf(w.x, f0.y, a0[1]);
    a0[2] = fmaf(w.x, f0.z, a0[2]); a0[3] = fmaf(w.x, f0.w, a0[3]);
    a0[4] = fmaf(w.x, f1.x, a0[4]); a0[5] = fmaf(w.x, f1.y, a0[5]);
    a0[6] = fmaf(w.x, f1.z, a0[6]); a0[7] = fmaf(w.x, f1.w, a0[7]);
    a1[0] = fmaf(w.y, f0.x, a1[0]); a1[1] = fmaf(w.y, f0.y, a1[1]);
    a1[2] = fmaf(w.y, f0.z, a1[2]); a1[3] = fmaf(w.y, f0.w, a1[3]);
    a1[4] = fmaf(w.y, f1.x, a1[4]); a1[5] = fmaf(w.y, f1.y, a1[5]);
    a1[6] = fmaf(w.y, f1.z, a1[6]); a1[7] = fmaf(w.y, f1.w, a1[7]);
  }
  {
    float c0 = bm[128 + o2], c1 = bm[128 + o2 + 1];
    float t0 = msc[128 + o2], t1 = msc[128 + o2 + 1];
    float q0 = mbi[128 + o2], q1 = mbi[128 + o2 + 1];
    float4 v0a, v0b, v1a, v1b;
    v0a.x = fmaxf(fmaf(a0[0] + c0, t0, q0), 0.f);
    v0a.y = fmaxf(fmaf(a0[1] + c0, t0, q0), 0.f);
    v0a.z = fmaxf(fmaf(a0[2] + c0, t0, q0), 0.f);
    v0a.w = fmaxf(fmaf(a0[3] + c0, t0, q0), 0.f);
    v0b.x = fmaxf(fmaf(a0[4] + c0, t0, q0), 0.f);
    v0b.y = fmaxf(fmaf(a0[5] + c0, t0, q0), 0.f);
    v0b.z = fmaxf(fmaf(a0[6] + c0, t0, q0), 0.f);
    v0b.w = fmaxf(fmaf(a0[7] + c0, t0, q0), 0.f);
    v1a.x = fmaxf(fmaf(a1[0] + c1, t1, q1), 0.f);
    v1a.y = fmaxf(fmaf(a1[1] + c1, t1, q1), 0.f);
    v1a.z = fmaxf(fmaf(a1[2] + c1, t1, q1), 0.f);
    v1a.w = fmaxf(fmaf(a1[3] + c1, t1, q1), 0.f);
    v1b.x = fmaxf(fmaf(a1[4] + c1, t1, q1), 0.f);
    v1b.y = fmaxf(fmaf(a1[5] + c1, t1, q1), 0.f);
    v1b.z = fmaxf(fmaf(a1[6] + c1, t1, q1), 0.f);
    v1b.w = fmaxf(fmaf(a1[7] + c1, t1, q1), 0.f);
    float* p0 = &out_feat[((size_t)b * 128 + o2) * 128 + sbase + s0];
    float* p1 = &out_feat[((size_t)b * 128 + o2 + 1) * 128 + sbase + s0];
    *(float4*)p0 = v0a;
    *(float4*)(p0 + 4) = v0b;
    *(float4*)p1 = v1a;
    *(float4*)(p1 + 4) = v1b;
  }
}

extern "C" void kernel_launch(void* const* d_in, const int* in_sizes, int n_in,
                              void* d_out, int out_size, void* d_ws, size_t ws_size,
                              hipStream_t stream) {
  const float* vote_xyz  = (const float*)d_in[0];
  const float* vote_feat = (const float*)d_in[1];
  const float* W1   = (const float*)d_in[2];
  const float* W2   = (const float*)d_in[3];
  const float* W3   = (const float*)d_in[4];
  const float* sasc = (const float*)d_in[5];
  const float* sabi = (const float*)d_in[6];
  const float* Wm   = (const float*)d_in[7];
  const float* bm   = (const float*)d_in[8];
  const float* msc  = (const float*)d_in[9];
  const float* mbi  = (const float*)d_in[10];

  float* out = (float*)d_out;
  float* out_xyz  = out;                    // B*NP*3   = 6144
  float* out_feat = out + 6144;             // B*128*NP = 262144
  float* out_indf = out + 6144 + 262144;    // B*NP     = 2048

  char* ws = (char*)d_ws;
  int*   fps_ws  = (int*)(ws + 0);          //   8 KB
  float* centers = (float*)(ws + 8192);     //  24 KB
  int*   bidx    = (int*)(ws + 32768);      // 128 KB
  float* W1T     = (float*)(ws + 163840);   // 132608 B
  float* W2T     = (float*)(ws + 296448);   //  64 KB
  float* W3T     = (float*)(ws + 361984);   //  64 KB
  float* WmT     = (float*)(ws + 427520);   // 128 KB
  float* feat0   = (float*)(ws + 558592);   //   1 MB

  hipLaunchKernelGGL(transpose_kernel, dim3(130), dim3(256), 0, stream,
                     W1, W2, W3, Wm, W1T, W2T, W3T, WmT);
  hipLaunchKernelGGL(fps_kernel, dim3(NB), dim3(1024), 0, stream,
                     vote_xyz, fps_ws, centers, out_xyz, out_indf);
  hipLaunchKernelGGL(ballq_kernel, dim3(NB * NPP), dim3(64), 0, stream,
                     vote_xyz, centers, bidx);
  hipLaunchKernelGGL(mlp_kernel, dim3(NB * NPP), dim3(256), 0, stream,
                     vote_xyz, vote_feat, centers, bidx, W1T, W2T, W3T,
                     sasc, sabi, feat0);
  hipLaunchKernelGGL(head_kernel, dim3(NB * 4), dim3(256), 0, stream,
                     feat0, WmT, bm, msc, mbi, out_feat);
}

// Round 2
// 445.118 us; speedup vs baseline: 1.1786x; 1.1786x over previous
//
#include <hip/hip_runtime.h>
#include <hip/hip_bf16.h>

#define NB  16
#define NN  16384
#define NC  256
#define NPP 128
#define NSS 16

#define FTH 512   // fps threads per block
#define FPT 32    // fps points per thread

// ---------------- weight transpose (one-shot, tiny) ----------------
__global__ __launch_bounds__(256) void transpose_kernel(
    const float* __restrict__ W1, const float* __restrict__ W2,
    const float* __restrict__ W3, const float* __restrict__ Wm,
    float* __restrict__ W1T, float* __restrict__ W2T,
    float* __restrict__ W3T, float* __restrict__ WmT) {
  int i = blockIdx.x * 256 + threadIdx.x;
  if (i < 128 * 259) { int o = i / 259, c = i - o * 259; W1T[c * 128 + o] = W1[i]; }
  if (i < 128 * 128) {
    int o = i >> 7, c = i & 127;
    W2T[c * 128 + o] = W2[i];
    W3T[c * 128 + o] = W3[i];
    WmT[c * 128 + o] = Wm[i];
    WmT[16384 + c * 128 + o] = Wm[16384 + i];
  }
}

// ---------------- FPS: one block per batch, ONE barrier per iteration ----
// Bit-exact vs numpy: d = ((dx*dx + dy*dy) + dz*dz), each op rounded (no FMA),
// argmax tie-break = lowest index via packed u64 atomicMax:
//   pack = (f32bits(val) << 32) | (0xFFFFFFFF - idx)
// (nonneg f32 bits are monotone unsigned; larger low word = smaller idx).
// Winner coords re-loaded from global by ALL threads (broadcast, L2-hit) so
// no second barrier is needed. Slot rotation (4 slots) makes the reset of a
// slot barrier-separated from its readers.
__global__ __launch_bounds__(FTH) void fps_kernel(
    const float* __restrict__ xyz, int* __restrict__ fps_ws,
    float* __restrict__ centers, float* __restrict__ out_xyz,
    float* __restrict__ out_indf) {
  int b = blockIdx.x;
  const float* px = xyz + (size_t)b * (NN * 3);
  int t = threadIdx.x;
  float X[FPT], Y[FPT], Z[FPT], MD[FPT];
#pragma unroll
  for (int j = 0; j < FPT; ++j) {
    int n = t + j * FTH;
    X[j] = px[n * 3 + 0];
    Y[j] = px[n * 3 + 1];
    Z[j] = px[n * 3 + 2];
    MD[j] = 1e10f;
  }
  __shared__ unsigned long long slot[4];
  if (t < 4) slot[t] = 0ull;
  float cx = px[0], cy = px[1], cz = px[2];
  if (t == 0) {
    fps_ws[b * NPP] = 0;
    out_indf[b * NPP] = 0.0f;
    centers[(b * NPP) * 3 + 0] = cx;
    centers[(b * NPP) * 3 + 1] = cy;
    centers[(b * NPP) * 3 + 2] = cz;
    out_xyz[(b * NPP) * 3 + 0] = cx;
    out_xyz[(b * NPP) * 3 + 1] = cy;
    out_xyz[(b * NPP) * 3 + 2] = cz;
  }
  __syncthreads();
  for (int it = 1; it < NPP; ++it) {
    float bv = -1.0f;
    int bi = 0;
#pragma unroll
    for (int j = 0; j < FPT; ++j) {
      float dx = __fsub_rn(X[j], cx);
      float dy = __fsub_rn(Y[j], cy);
      float dz = __fsub_rn(Z[j], cz);
      float d  = __fadd_rn(__fadd_rn(__fmul_rn(dx, dx), __fmul_rn(dy, dy)),
                           __fmul_rn(dz, dz));
      float m = fminf(MD[j], d);
      MD[j] = m;
      if (m > bv) { bv = m; bi = t + j * FTH; }
    }
#pragma unroll
    for (int off = 1; off < 64; off <<= 1) {
      float ov = __shfl_xor(bv, off, 64);
      int   oi = __shfl_xor(bi, off, 64);
      if (ov > bv || (ov == bv && oi < bi)) { bv = ov; bi = oi; }
    }
    if ((t & 63) == 0) {
      unsigned long long pk =
          (((unsigned long long)__float_as_uint(bv)) << 32) |
          (unsigned long long)(0xFFFFFFFFu - (unsigned)bi);
      atomicMax(&slot[it & 3], pk);
    }
    if (t == FTH - 1) slot[(it + 2) & 3] = 0ull;
    __syncthreads();
    unsigned long long pk = slot[it & 3];
    int win = (int)(0xFFFFFFFFu - (unsigned)(pk & 0xFFFFFFFFull));
    cx = px[win * 3 + 0];
    cy = px[win * 3 + 1];
    cz = px[win * 3 + 2];
    if (t == 0) {
      fps_ws[b * NPP + it] = win;
      out_indf[b * NPP + it] = (float)win;
      centers[(b * NPP + it) * 3 + 0] = cx;
      centers[(b * NPP + it) * 3 + 1] = cy;
      centers[(b * NPP + it) * 3 + 2] = cz;
      out_xyz[(b * NPP + it) * 3 + 0] = cx;
      out_xyz[(b * NPP + it) * 3 + 1] = cy;
      out_xyz[(b * NPP + it) * 3 + 2] = cz;
    }
  }
}

// ---------------- ball query: one wave per (b, center) ----------------
__global__ __launch_bounds__(64) void ballq_kernel(
    const float* __restrict__ xyz, const float* __restrict__ centers,
    int* __restrict__ bidx) {
  int bs = blockIdx.x;  // b*128 + s
  int b = bs >> 7;
  int lane = threadIdx.x;
  const float* px = xyz + (size_t)b * (NN * 3);
  float cx = centers[bs * 3 + 0];
  float cy = centers[bs * 3 + 1];
  float cz = centers[bs * 3 + 2];
  __shared__ int coll[NSS];
  const float rr = 0.09f;  // f32(0.09): identical membership to f64 compare
  int have = 0;
  for (int c0 = 0; c0 < NN; c0 += 64) {
    int n = c0 + lane;
    float dx = __fsub_rn(px[n * 3 + 0], cx);
    float dy = __fsub_rn(px[n * 3 + 1], cy);
    float dz = __fsub_rn(px[n * 3 + 2], cz);
    float d2 = __fadd_rn(__fadd_rn(__fmul_rn(dx, dx), __fmul_rn(dy, dy)),
                         __fmul_rn(dz, dz));
    bool in = d2 < rr;
    unsigned long long m = __ballot(in);
    if (in) {
      int pos = have + __popcll(m & ((1ull << lane) - 1ull));
      if (pos < NSS) coll[pos] = n;
    }
    have += __popcll(m);
    if (have >= NSS) break;
  }
  __syncthreads();
  int first = coll[0];
  if (lane < NSS) bidx[bs * NSS + lane] = (lane < have) ? coll[lane] : first;
}

// ---------------- grouped MLP (3 layers + maxpool over NS) ----------------
__device__ __forceinline__ void layer_f(const float (*in)[20], int cin,
                                        const float* __restrict__ WT,
                                        const float* __restrict__ sc,
                                        const float* __restrict__ bi,
                                        int o2, int k0, float4& r0, float4& r1) {
  float a0[4] = {0.f, 0.f, 0.f, 0.f};
  float a1[4] = {0.f, 0.f, 0.f, 0.f};
  for (int c = 0; c < cin; ++c) {
    float2 w = *(const float2*)(WT + c * 128 + o2);
    float4 gv = *(const float4*)(&in[c][k0]);
    a0[0] = fmaf(w.x, gv.x, a0[0]);
    a0[1] = fmaf(w.x, gv.y, a0[1]);
    a0[2] = fmaf(w.x, gv.z, a0[2]);
    a0[3] = fmaf(w.x, gv.w, a0[3]);
    a1[0] = fmaf(w.y, gv.x, a1[0]);
    a1[1] = fmaf(w.y, gv.y, a1[1]);
    a1[2] = fmaf(w.y, gv.z, a1[2]);
    a1[3] = fmaf(w.y, gv.w, a1[3]);
  }
  float s0 = sc[o2], s1 = sc[o2 + 1], b0 = bi[o2], b1 = bi[o2 + 1];
  r0.x = fmaxf(fmaf(a0[0], s0, b0), 0.f);
  r0.y = fmaxf(fmaf(a0[1], s0, b0), 0.f);
  r0.z = fmaxf(fmaf(a0[2], s0, b0), 0.f);
  r0.w = fmaxf(fmaf(a0[3], s0, b0), 0.f);
  r1.x = fmaxf(fmaf(a1[0], s1, b1), 0.f);
  r1.y = fmaxf(fmaf(a1[1], s1, b1), 0.f);
  r1.z = fmaxf(fmaf(a1[2], s1, b1), 0.f);
  r1.w = fmaxf(fmaf(a1[3], s1, b1), 0.f);
}

__global__ __launch_bounds__(256) void mlp_kernel(
    const float* __restrict__ xyz, const float* __restrict__ feats,
    const float* __restrict__ centers, const int* __restrict__ bidx,
    const float* __restrict__ W1T, const float* __restrict__ W2T,
    const float* __restrict__ W3T, const float* __restrict__ sa_sc,
    const float* __restrict__ sa_bi, float* __restrict__ feat0) {
  int bs = blockIdx.x;
  int b = bs >> 7;
  int s = bs & 127;
  int tid = threadIdx.x;
  __shared__ float g[259][20];
  __shared__ float h1[128][20];
  __shared__ float h2[128][20];
  __shared__ int kidx[NSS];
  __shared__ float ctr[3];
  if (tid < NSS) kidx[tid] = bidx[bs * NSS + tid];
  if (tid < 3) ctr[tid] = centers[bs * 3 + tid];
  __syncthreads();
  const float* px = xyz + (size_t)b * (NN * 3);
  if (tid < NSS) {
    int n = kidx[tid];
    g[0][tid] = __fdiv_rn(__fsub_rn(px[n * 3 + 0], ctr[0]), 0.3f);
    g[1][tid] = __fdiv_rn(__fsub_rn(px[n * 3 + 1], ctr[1]), 0.3f);
    g[2][tid] = __fdiv_rn(__fsub_rn(px[n * 3 + 2], ctr[2]), 0.3f);
  }
  {
    const float* row = feats + ((size_t)b * NC + tid) * NN;
#pragma unroll
    for (int k = 0; k < NSS; ++k) g[3 + tid][k] = row[kidx[k]];
  }
  __syncthreads();
  int o2 = (tid & 63) * 2;
  int k0 = (tid >> 6) * 4;
  float4 r0, r1;
  layer_f(g, 259, W1T, sa_sc, sa_bi, o2, k0, r0, r1);
  *(float4*)&h1[o2][k0] = r0;
  *(float4*)&h1[o2 + 1][k0] = r1;
  __syncthreads();
  layer_f(h1, 128, W2T, sa_sc + 128, sa_bi + 128, o2, k0, r0, r1);
  *(float4*)&h2[o2][k0] = r0;
  *(float4*)&h2[o2 + 1][k0] = r1;
  __syncthreads();
  layer_f(h2, 128, W3T, sa_sc + 256, sa_bi + 256, o2, k0, r0, r1);
  float m0 = fmaxf(fmaxf(r0.x, r0.y), fmaxf(r0.z, r0.w));
  float m1 = fmaxf(fmaxf(r1.x, r1.y), fmaxf(r1.z, r1.w));
  int w = tid >> 6;
  h1[o2][w] = m0;
  h1[o2 + 1][w] = m1;
  __syncthreads();
  if (tid < 128) {
    float m = fmaxf(fmaxf(h1[tid][0], h1[tid][1]), fmaxf(h1[tid][2], h1[tid][3]));
    feat0[((size_t)b * 128 + tid) * 128 + s] = m;
  }
}

// ---------------- FC heads: (x@Wm + bm)*scale + bias, relu, x2 ----------------
__global__ __launch_bounds__(256) void head_kernel(
    const float* __restrict__ feat0, const float* __restrict__ WmT,
    const float* __restrict__ bm, const float* __restrict__ msc,
    const float* __restrict__ mbi, float* __restrict__ out_feat) {
  int blk = blockIdx.x;
  int b = blk >> 2;
  int sbase = (blk & 3) * 32;
  int tid = threadIdx.x;
  __shared__ float fa[128][36];
  __shared__ float fb[128][36];
  {
    int sj = tid & 31, c0 = tid >> 5;
    for (int c = c0; c < 128; c += 8)
      fa[c][sj] = feat0[((size_t)b * 128 + c) * 128 + sbase + sj];
  }
  __syncthreads();
  int o2 = (tid & 63) * 2, s0 = (tid >> 6) * 8;
  float a0[8], a1[8];
#pragma unroll
  for (int j = 0; j < 8; ++j) { a0[j] = 0.f; a1[j] = 0.f; }
  for (int c = 0; c < 128; ++c) {
    float2 w = *(const float2*)&WmT[c * 128 + o2];
    float4 f0 = *(const float4*)&fa[c][s0];
    float4 f1 = *(const float4*)&fa[c][s0 + 4];
    a0[0] = fmaf(w.x, f0.x, a0[0]); a0[1] = fmaf(w.x, f0.y, a0[1]);
    a0[2] = fmaf(w.x, f0.z, a0[2]); a0[3] = fmaf(w.x, f0.w, a0[3]);
    a0[4] = fmaf(w.x, f1.x, a0[4]); a0[5] = fmaf(w.x, f1.y, a0[5]);
    a0[6] = fmaf(w.x, f1.z, a0[6]); a0[7] = fmaf(w.x, f1.w, a0[7]);
    a1[0] = fmaf(w.y, f0.x, a1[0]); a1[1] = fmaf(w.y, f0.y, a1[1]);
    a1[2] = fmaf(w.y, f0.z, a1[2]); a1[3] = fmaf(w.y, f0.w, a1[3]);
    a1[4] = fmaf(w.y, f1.x, a1[4]); a1[5] = fmaf(w.y, f1.y, a1[5]);
    a1[6] = fmaf(w.y, f1.z, a1[6]); a1[7] = fmaf(w.y, f1.w, a1[7]);
  }
  {
    float c0 = bm[o2], c1 = bm[o2 + 1];
    float t0 = msc[o2], t1 = msc[o2 + 1];
    float q0 = mbi[o2], q1 = mbi[o2 + 1];
#pragma unroll
    for (int j = 0; j < 8; ++j) {
      fb[o2][s0 + j]     = fmaxf(fmaf(a0[j] + c0, t0, q0), 0.f);
      fb[o2 + 1][s0 + j] = fmaxf(fmaf(a1[j] + c1, t1, q1), 0.f);
    }
  }
  __syncthreads();
#pragma unroll
  for (int j = 0; j < 8; ++j) { a0[j] = 0.f; a1[j] = 0.f; }
  for (int c = 0; c < 128; ++c) {
    float2 w = *(const float2*)&WmT[16384 + c * 128 + o2];
    float4 f0 = *(const float4*)&fb[c][s0];
    float4 f1 = *(const float4*)&fb[c][s0 + 4];
    a0[0] = fmaf(w.x, f0.x, a0[0]); a0[1] = fmaf(w.x, f0.y, a0[1]);
    a0[2] = fmaf(w.x, f0.z, a0[2]); a0[3] = fmaf(w.x, f0.w, a0[3]);
    a0[4] = fmaf(w.x, f1.x, a0[4]); a0[5] = fmaf(w.x, f1.y, a0[5]);
    a0[6] = fmaf(w.x, f1.z, a0[6]); a0[7] = fmaf(w.x, f1.w, a0[7]);
    a1[0] = fmaf(w.y, f0.x, a1[0]); a1[1] = fmaf(w.y, f0.y, a1[1]);
    a1[2] = fmaf(w.y, f0.z, a1[2]); a1[3] = fmaf(w.y, f0.w, a1[3]);
    a1[4] = fmaf(w.y, f1.x, a1[4]); a1[5] = fmaf(w.y, f1.y, a1[5]);
    a1[6] = fmaf(w.y, f1.z, a1[6]); a1[7] = fmaf(w.y, f1.w, a1[7]);
  }
  {
    float c0 = bm[128 + o2], c1 = bm[128 + o2 + 1];
    float t0 = msc[128 + o2], t1 = msc[128 + o2 + 1];
    float q0 = mbi[128 + o2], q1 = mbi[128 + o2 + 1];
    float4 v0a, v0b, v1a, v1b;
    v0a.x = fmaxf(fmaf(a0[0] + c0, t0, q0), 0.f);
    v0a.y = fmaxf(fmaf(a0[1] + c0, t0, q0), 0.f);
    v0a.z = fmaxf(fmaf(a0[2] + c0, t0, q0), 0.f);
    v0a.w = fmaxf(fmaf(a0[3] + c0, t0, q0), 0.f);
    v0b.x = fmaxf(fmaf(a0[4] + c0, t0, q0), 0.f);
    v0b.y = fmaxf(fmaf(a0[5] + c0, t0, q0), 0.f);
    v0b.z = fmaxf(fmaf(a0[6] + c0, t0, q0), 0.f);
    v0b.w = fmaxf(fmaf(a0[7] + c0, t0, q0), 0.f);
    v1a.x = fmaxf(fmaf(a1[0] + c1, t1, q1), 0.f);
    v1a.y = fmaxf(fmaf(a1[1] + c1, t1, q1), 0.f);
    v1a.z = fmaxf(fmaf(a1[2] + c1, t1, q1), 0.f);
    v1a.w = fmaxf(fmaf(a1[3] + c1, t1, q1), 0.f);
    v1b.x = fmaxf(fmaf(a1[4] + c1, t1, q1), 0.f);
    v1b.y = fmaxf(fmaf(a1[5] + c1, t1, q1), 0.f);
    v1b.z = fmaxf(fmaf(a1[6] + c1, t1, q1), 0.f);
    v1b.w = fmaxf(fmaf(a1[7] + c1, t1, q1), 0.f);
    float* p0 = &out_feat[((size_t)b * 128 + o2) * 128 + sbase + s0];
    float* p1 = &out_feat[((size_t)b * 128 + o2 + 1) * 128 + sbase + s0];
    *(float4*)p0 = v0a;
    *(float4*)(p0 + 4) = v0b;
    *(float4*)p1 = v1a;
    *(float4*)(p1 + 4) = v1b;
  }
}

extern "C" void kernel_launch(void* const* d_in, const int* in_sizes, int n_in,
                              void* d_out, int out_size, void* d_ws, size_t ws_size,
                              hipStream_t stream) {
  const float* vote_xyz  = (const float*)d_in[0];
  const float* vote_feat = (const float*)d_in[1];
  const float* W1   = (const float*)d_in[2];
  const float* W2   = (const float*)d_in[3];
  const float* W3   = (const float*)d_in[4];
  const float* sasc = (const float*)d_in[5];
  const float* sabi = (const float*)d_in[6];
  const float* Wm   = (const float*)d_in[7];
  const float* bm   = (const float*)d_in[8];
  const float* msc  = (const float*)d_in[9];
  const float* mbi  = (const float*)d_in[10];

  float* out = (float*)d_out;
  float* out_xyz  = out;                    // B*NP*3   = 6144
  float* out_feat = out + 6144;             // B*128*NP = 262144
  float* out_indf = out + 6144 + 262144;    // B*NP     = 2048

  char* ws = (char*)d_ws;
  int*   fps_ws  = (int*)(ws + 0);          //   8 KB
  float* centers = (float*)(ws + 8192);     //  24 KB
  int*   bidx    = (int*)(ws + 32768);      // 128 KB
  float* W1T     = (float*)(ws + 163840);   // 132608 B
  float* W2T     = (float*)(ws + 296448);   //  64 KB
  float* W3T     = (float*)(ws + 361984);   //  64 KB
  float* WmT     = (float*)(ws + 427520);   // 128 KB
  float* feat0   = (float*)(ws + 558592);   //   1 MB

  hipLaunchKernelGGL(transpose_kernel, dim3(130), dim3(256), 0, stream,
                     W1, W2, W3, Wm, W1T, W2T, W3T, WmT);
  hipLaunchKernelGGL(fps_kernel, dim3(NB), dim3(FTH), 0, stream,
                     vote_xyz, fps_ws, centers, out_xyz, out_indf);
  hipLaunchKernelGGL(ballq_kernel, dim3(NB * NPP), dim3(64), 0, stream,
                     vote_xyz, centers, bidx);
  hipLaunchKernelGGL(mlp_kernel, dim3(NB * NPP), dim3(256), 0, stream,
                     vote_xyz, vote_feat, centers, bidx, W1T, W2T, W3T,
                     sasc, sabi, feat0);
  hipLaunchKernelGGL(head_kernel, dim3(NB * 4), dim3(256), 0, stream,
                     feat0, WmT, bm, msc, mbi, out_feat);
}

// Round 3
// 409.857 us; speedup vs baseline: 1.2800x; 1.0860x over previous
//
#include <hip/hip_runtime.h>
#include <hip/hip_bf16.h>

#define NB  16
#define NN  16384
#define NC  256
#define NPP 128
#define NSS 16

#define FTH 512   // fps threads per block (8 waves)
#define FPT 32    // fps points per thread

// ---------------- weight transpose (one-shot, tiny) ----------------
__global__ __launch_bounds__(256) void transpose_kernel(
    const float* __restrict__ W1, const float* __restrict__ W2,
    const float* __restrict__ W3, const float* __restrict__ Wm,
    float* __restrict__ W1T, float* __restrict__ W2T,
    float* __restrict__ W3T, float* __restrict__ WmT) {
  int i = blockIdx.x * 256 + threadIdx.x;
  if (i < 128 * 259) { int o = i / 259, c = i - o * 259; W1T[c * 128 + o] = W1[i]; }
  if (i < 128 * 128) {
    int o = i >> 7, c = i & 127;
    W2T[c * 128 + o] = W2[i];
    W3T[c * 128 + o] = W3[i];
    WmT[c * 128 + o] = Wm[i];
    WmT[16384 + c * 128 + o] = Wm[16384 + i];
  }
}

// ---------------- FPS: one block per batch, ONE barrier per iteration ----
// Bit-exact vs numpy: d = ((dx*dx + dy*dy) + dz*dz), each op rounded (no FMA),
// argmax tie-break = lowest index via packed u64 max:
//   pack = (f32bits(val) << 32) | (0xFFFFFFFF - idx)
// (nonneg f32 bits monotone as unsigned; larger low word = smaller idx).
// Per-wave u64 butterfly -> 8 LDS candidates (double-buffered by parity) ->
// one barrier -> every thread scans 8 candidates -> scalar re-load of winner
// coords from global (L2-resident).
// __launch_bounds__(512,2): VGPR cap 256 so X/Y/Z/MD (128 regs) do NOT spill.
__global__ __launch_bounds__(FTH, 2) void fps_kernel(
    const float* __restrict__ xyz, int* __restrict__ fps_ws,
    float* __restrict__ centers, float* __restrict__ out_xyz,
    float* __restrict__ out_indf) {
  int b = blockIdx.x;
  const float* px = xyz + (size_t)b * (NN * 3);
  int t = threadIdx.x;
  float X[FPT], Y[FPT], Z[FPT], MD[FPT];
#pragma unroll
  for (int j = 0; j < FPT; ++j) {
    int n = t + j * FTH;
    X[j] = px[n * 3 + 0];
    Y[j] = px[n * 3 + 1];
    Z[j] = px[n * 3 + 2];
    MD[j] = 1e10f;
  }
  __shared__ unsigned long long cand[2][8];
  float cx = px[0], cy = px[1], cz = px[2];
  if (t == 0) {
    fps_ws[b * NPP] = 0;
    out_indf[b * NPP] = 0.0f;
    centers[(b * NPP) * 3 + 0] = cx;
    centers[(b * NPP) * 3 + 1] = cy;
    centers[(b * NPP) * 3 + 2] = cz;
    out_xyz[(b * NPP) * 3 + 0] = cx;
    out_xyz[(b * NPP) * 3 + 1] = cy;
    out_xyz[(b * NPP) * 3 + 2] = cz;
  }
  for (int it = 1; it < NPP; ++it) {
    float bv = -1.0f;
    int bi = 0;
#pragma unroll
    for (int j = 0; j < FPT; ++j) {
      float dx = __fsub_rn(X[j], cx);
      float dy = __fsub_rn(Y[j], cy);
      float dz = __fsub_rn(Z[j], cz);
      float d  = __fadd_rn(__fadd_rn(__fmul_rn(dx, dx), __fmul_rn(dy, dy)),
                           __fmul_rn(dz, dz));
      float m = fminf(MD[j], d);
      MD[j] = m;
      if (m > bv) { bv = m; bi = t + j * FTH; }  // first occurrence kept
    }
    unsigned long long pk =
        (((unsigned long long)__float_as_uint(bv)) << 32) |
        (unsigned long long)(0xFFFFFFFFu - (unsigned)bi);
#pragma unroll
    for (int off = 1; off < 64; off <<= 1) {
      unsigned long long o = __shfl_xor(pk, off, 64);
      if (o > pk) pk = o;
    }
    if ((t & 63) == 0) cand[it & 1][t >> 6] = pk;
    __syncthreads();
    const unsigned long long* cp = cand[it & 1];
    unsigned long long mx = cp[0];
#pragma unroll
    for (int w = 1; w < 8; ++w) {
      unsigned long long v = cp[w];
      if (v > mx) mx = v;
    }
    int win = (int)(0xFFFFFFFFu - (unsigned)(mx & 0xFFFFFFFFull));
    win = __builtin_amdgcn_readfirstlane(win);
    cx = px[win * 3 + 0];
    cy = px[win * 3 + 1];
    cz = px[win * 3 + 2];
    if (t == 0) {
      fps_ws[b * NPP + it] = win;
      out_indf[b * NPP + it] = (float)win;
      centers[(b * NPP + it) * 3 + 0] = cx;
      centers[(b * NPP + it) * 3 + 1] = cy;
      centers[(b * NPP + it) * 3 + 2] = cz;
      out_xyz[(b * NPP + it) * 3 + 0] = cx;
      out_xyz[(b * NPP + it) * 3 + 1] = cy;
      out_xyz[(b * NPP + it) * 3 + 2] = cz;
    }
  }
}

// ---------------- ball query: one wave per (b, center) ----------------
__global__ __launch_bounds__(64) void ballq_kernel(
    const float* __restrict__ xyz, const float* __restrict__ centers,
    int* __restrict__ bidx) {
  int bs = blockIdx.x;  // b*128 + s
  int b = bs >> 7;
  int lane = threadIdx.x;
  const float* px = xyz + (size_t)b * (NN * 3);
  float cx = centers[bs * 3 + 0];
  float cy = centers[bs * 3 + 1];
  float cz = centers[bs * 3 + 2];
  __shared__ int coll[NSS];
  const float rr = 0.09f;  // f32(0.09): identical membership to f64 compare
  int have = 0;
  for (int c0 = 0; c0 < NN; c0 += 64) {
    int n = c0 + lane;
    float dx = __fsub_rn(px[n * 3 + 0], cx);
    float dy = __fsub_rn(px[n * 3 + 1], cy);
    float dz = __fsub_rn(px[n * 3 + 2], cz);
    float d2 = __fadd_rn(__fadd_rn(__fmul_rn(dx, dx), __fmul_rn(dy, dy)),
                         __fmul_rn(dz, dz));
    bool in = d2 < rr;
    unsigned long long m = __ballot(in);
    if (in) {
      int pos = have + __popcll(m & ((1ull << lane) - 1ull));
      if (pos < NSS) coll[pos] = n;
    }
    have += __popcll(m);
    if (have >= NSS) break;
  }
  __syncthreads();
  int first = coll[0];
  if (lane < NSS) bidx[bs * NSS + lane] = (lane < have) ? coll[lane] : first;
}

// ---------------- grouped MLP (3 layers + maxpool over NS) ----------------
__device__ __forceinline__ void layer_f(const float (*in)[20], int cin,
                                        const float* __restrict__ WT,
                                        const float* __restrict__ sc,
                                        const float* __restrict__ bi,
                                        int o2, int k0, float4& r0, float4& r1) {
  float a0[4] = {0.f, 0.f, 0.f, 0.f};
  float a1[4] = {0.f, 0.f, 0.f, 0.f};
  for (int c = 0; c < cin; ++c) {
    float2 w = *(const float2*)(WT + c * 128 + o2);
    float4 gv = *(const float4*)(&in[c][k0]);
    a0[0] = fmaf(w.x, gv.x, a0[0]);
    a0[1] = fmaf(w.x, gv.y, a0[1]);
    a0[2] = fmaf(w.x, gv.z, a0[2]);
    a0[3] = fmaf(w.x, gv.w, a0[3]);
    a1[0] = fmaf(w.y, gv.x, a1[0]);
    a1[1] = fmaf(w.y, gv.y, a1[1]);
    a1[2] = fmaf(w.y, gv.z, a1[2]);
    a1[3] = fmaf(w.y, gv.w, a1[3]);
  }
  float s0 = sc[o2], s1 = sc[o2 + 1], b0 = bi[o2], b1 = bi[o2 + 1];
  r0.x = fmaxf(fmaf(a0[0], s0, b0), 0.f);
  r0.y = fmaxf(fmaf(a0[1], s0, b0), 0.f);
  r0.z = fmaxf(fmaf(a0[2], s0, b0), 0.f);
  r0.w = fmaxf(fmaf(a0[3], s0, b0), 0.f);
  r1.x = fmaxf(fmaf(a1[0], s1, b1), 0.f);
  r1.y = fmaxf(fmaf(a1[1], s1, b1), 0.f);
  r1.z = fmaxf(fmaf(a1[2], s1, b1), 0.f);
  r1.w = fmaxf(fmaf(a1[3], s1, b1), 0.f);
}

__global__ __launch_bounds__(256) void mlp_kernel(
    const float* __restrict__ xyz, const float* __restrict__ feats,
    const float* __restrict__ centers, const int* __restrict__ bidx,
    const float* __restrict__ W1T, const float* __restrict__ W2T,
    const float* __restrict__ W3T, const float* __restrict__ sa_sc,
    const float* __restrict__ sa_bi, float* __restrict__ feat0) {
  int bs = blockIdx.x;
  int b = bs >> 7;
  int s = bs & 127;
  int tid = threadIdx.x;
  __shared__ float g[259][20];
  __shared__ float h1[128][20];
  __shared__ float h2[128][20];
  __shared__ int kidx[NSS];
  __shared__ float ctr[3];
  if (tid < NSS) kidx[tid] = bidx[bs * NSS + tid];
  if (tid < 3) ctr[tid] = centers[bs * 3 + tid];
  __syncthreads();
  const float* px = xyz + (size_t)b * (NN * 3);
  if (tid < NSS) {
    int n = kidx[tid];
    g[0][tid] = __fdiv_rn(__fsub_rn(px[n * 3 + 0], ctr[0]), 0.3f);
    g[1][tid] = __fdiv_rn(__fsub_rn(px[n * 3 + 1], ctr[1]), 0.3f);
    g[2][tid] = __fdiv_rn(__fsub_rn(px[n * 3 + 2], ctr[2]), 0.3f);
  }
  {
    const float* row = feats + ((size_t)b * NC + tid) * NN;
#pragma unroll
    for (int k = 0; k < NSS; ++k) g[3 + tid][k] = row[kidx[k]];
  }
  __syncthreads();
  int o2 = (tid & 63) * 2;
  int k0 = (tid >> 6) * 4;
  float4 r0, r1;
  layer_f(g, 259, W1T, sa_sc, sa_bi, o2, k0, r0, r1);
  *(float4*)&h1[o2][k0] = r0;
  *(float4*)&h1[o2 + 1][k0] = r1;
  __syncthreads();
  layer_f(h1, 128, W2T, sa_sc + 128, sa_bi + 128, o2, k0, r0, r1);
  *(float4*)&h2[o2][k0] = r0;
  *(float4*)&h2[o2 + 1][k0] = r1;
  __syncthreads();
  layer_f(h2, 128, W3T, sa_sc + 256, sa_bi + 256, o2, k0, r0, r1);
  float m0 = fmaxf(fmaxf(r0.x, r0.y), fmaxf(r0.z, r0.w));
  float m1 = fmaxf(fmaxf(r1.x, r1.y), fmaxf(r1.z, r1.w));
  int w = tid >> 6;
  h1[o2][w] = m0;
  h1[o2 + 1][w] = m1;
  __syncthreads();
  if (tid < 128) {
    float m = fmaxf(fmaxf(h1[tid][0], h1[tid][1]), fmaxf(h1[tid][2], h1[tid][3]));
    feat0[((size_t)b * 128 + tid) * 128 + s] = m;
  }
}

// ---------------- FC heads: (x@Wm + bm)*scale + bias, relu, x2 ----------------
__global__ __launch_bounds__(256) void head_kernel(
    const float* __restrict__ feat0, const float* __restrict__ WmT,
    const float* __restrict__ bm, const float* __restrict__ msc,
    const float* __restrict__ mbi, float* __restrict__ out_feat) {
  int blk = blockIdx.x;
  int b = blk >> 2;
  int sbase = (blk & 3) * 32;
  int tid = threadIdx.x;
  __shared__ float fa[128][36];
  __shared__ float fb[128][36];
  {
    int sj = tid & 31, c0 = tid >> 5;
    for (int c = c0; c < 128; c += 8)
      fa[c][sj] = feat0[((size_t)b * 128 + c) * 128 + sbase + sj];
  }
  __syncthreads();
  int o2 = (tid & 63) * 2, s0 = (tid >> 6) * 8;
  float a0[8], a1[8];
#pragma unroll
  for (int j = 0; j < 8; ++j) { a0[j] = 0.f; a1[j] = 0.f; }
  for (int c = 0; c < 128; ++c) {
    float2 w = *(const float2*)&WmT[c * 128 + o2];
    float4 f0 = *(const float4*)&fa[c][s0];
    float4 f1 = *(const float4*)&fa[c][s0 + 4];
    a0[0] = fmaf(w.x, f0.x, a0[0]); a0[1] = fmaf(w.x, f0.y, a0[1]);
    a0[2] = fmaf(w.x, f0.z, a0[2]); a0[3] = fmaf(w.x, f0.w, a0[3]);
    a0[4] = fmaf(w.x, f1.x, a0[4]); a0[5] = fmaf(w.x, f1.y, a0[5]);
    a0[6] = fmaf(w.x, f1.z, a0[6]); a0[7] = fmaf(w.x, f1.w, a0[7]);
    a1[0] = fmaf(w.y, f0.x, a1[0]); a1[1] = fmaf(w.y, f0.y, a1[1]);
    a1[2] = fmaf(w.y, f0.z, a1[2]); a1[3] = fmaf(w.y, f0.w, a1[3]);
    a1[4] = fmaf(w.y, f1.x, a1[4]); a1[5] = fmaf(w.y, f1.y, a1[5]);
    a1[6] = fmaf(w.y, f1.z, a1[6]); a1[7] = fmaf(w.y, f1.w, a1[7]);
  }
  {
    float c0 = bm[o2], c1 = bm[o2 + 1];
    float t0 = msc[o2], t1 = msc[o2 + 1];
    float q0 = mbi[o2], q1 = mbi[o2 + 1];
#pragma unroll
    for (int j = 0; j < 8; ++j) {
      fb[o2][s0 + j]     = fmaxf(fmaf(a0[j] + c0, t0, q0), 0.f);
      fb[o2 + 1][s0 + j] = fmaxf(fmaf(a1[j] + c1, t1, q1), 0.f);
    }
  }
  __syncthreads();
#pragma unroll
  for (int j = 0; j < 8; ++j) { a0[j] = 0.f; a1[j] = 0.f; }
  for (int c = 0; c < 128; ++c) {
    float2 w = *(const float2*)&WmT[16384 + c * 128 + o2];
    float4 f0 = *(const float4*)&fb[c][s0];
    float4 f1 = *(const float4*)&fb[c][s0 + 4];
    a0[0] = fmaf(w.x, f0.x, a0[0]); a0[1] = fmaf(w.x, f0.y, a0[1]);
    a0[2] = fmaf(w.x, f0.z, a0[2]); a0[3] = fmaf(w.x, f0.w, a0[3]);
    a0[4] = fmaf(w.x, f1.x, a0[4]); a0[5] = fmaf(w.x, f1.y, a0[5]);
    a0[6] = fmaf(w.x, f1.z, a0[6]); a0[7] = fmaf(w.x, f1.w, a0[7]);
    a1[0] = fmaf(w.y, f0.x, a1[0]); a1[1] = fmaf(w.y, f0.y, a1[1]);
    a1[2] = fmaf(w.y, f0.z, a1[2]); a1[3] = fmaf(w.y, f0.w, a1[3]);
    a1[4] = fmaf(w.y, f1.x, a1[4]); a1[5] = fmaf(w.y, f1.y, a1[5]);
    a1[6] = fmaf(w.y, f1.z, a1[6]); a1[7] = fmaf(w.y, f1.w, a1[7]);
  }
  {
    float c0 = bm[128 + o2], c1 = bm[128 + o2 + 1];
    float t0 = msc[128 + o2], t1 = msc[128 + o2 + 1];
    float q0 = mbi[128 + o2], q1 = mbi[128 + o2 + 1];
    float4 v0a, v0b, v1a, v1b;
    v0a.x = fmaxf(fmaf(a0[0] + c0, t0, q0), 0.f);
    v0a.y = fmaxf(fmaf(a0[1] + c0, t0, q0), 0.f);
    v0a.z = fmaxf(fmaf(a0[2] + c0, t0, q0), 0.f);
    v0a.w = fmaxf(fmaf(a0[3] + c0, t0, q0), 0.f);
    v0b.x = fmaxf(fmaf(a0[4] + c0, t0, q0), 0.f);
    v0b.y = fmaxf(fmaf(a0[5] + c0, t0, q0), 0.f);
    v0b.z = fmaxf(fmaf(a0[6] + c0, t0, q0), 0.f);
    v0b.w = fmaxf(fmaf(a0[7] + c0, t0, q0), 0.f);
    v1a.x = fmaxf(fmaf(a1[0] + c1, t1, q1), 0.f);
    v1a.y = fmaxf(fmaf(a1[1] + c1, t1, q1), 0.f);
    v1a.z = fmaxf(fmaf(a1[2] + c1, t1, q1), 0.f);
    v1a.w = fmaxf(fmaf(a1[3] + c1, t1, q1), 0.f);
    v1b.x = fmaxf(fmaf(a1[4] + c1, t1, q1), 0.f);
    v1b.y = fmaxf(fmaf(a1[5] + c1, t1, q1), 0.f);
    v1b.z = fmaxf(fmaf(a1[6] + c1, t1, q1), 0.f);
    v1b.w = fmaxf(fmaf(a1[7] + c1, t1, q1), 0.f);
    float* p0 = &out_feat[((size_t)b * 128 + o2) * 128 + sbase + s0];
    float* p1 = &out_feat[((size_t)b * 128 + o2 + 1) * 128 + sbase + s0];
    *(float4*)p0 = v0a;
    *(float4*)(p0 + 4) = v0b;
    *(float4*)p1 = v1a;
    *(float4*)(p1 + 4) = v1b;
  }
}

extern "C" void kernel_launch(void* const* d_in, const int* in_sizes, int n_in,
                              void* d_out, int out_size, void* d_ws, size_t ws_size,
                              hipStream_t stream) {
  const float* vote_xyz  = (const float*)d_in[0];
  const float* vote_feat = (const float*)d_in[1];
  const float* W1   = (const float*)d_in[2];
  const float* W2   = (const float*)d_in[3];
  const float* W3   = (const float*)d_in[4];
  const float* sasc = (const float*)d_in[5];
  const float* sabi = (const float*)d_in[6];
  const float* Wm   = (const float*)d_in[7];
  const float* bm   = (const float*)d_in[8];
  const float* msc  = (const float*)d_in[9];
  const float* mbi  = (const float*)d_in[10];

  float* out = (float*)d_out;
  float* out_xyz  = out;                    // B*NP*3   = 6144
  float* out_feat = out + 6144;             // B*128*NP = 262144
  float* out_indf = out + 6144 + 262144;    // B*NP     = 2048

  char* ws = (char*)d_ws;
  int*   fps_ws  = (int*)(ws + 0);          //   8 KB
  float* centers = (float*)(ws + 8192);     //  24 KB
  int*   bidx    = (int*)(ws + 32768);      // 128 KB
  float* W1T     = (float*)(ws + 163840);   // 132608 B
  float* W2T     = (float*)(ws + 296448);   //  64 KB
  float* W3T     = (float*)(ws + 361984);   //  64 KB
  float* WmT     = (float*)(ws + 427520);   // 128 KB
  float* feat0   = (float*)(ws + 558592);   //   1 MB

  hipLaunchKernelGGL(transpose_kernel, dim3(130), dim3(256), 0, stream,
                     W1, W2, W3, Wm, W1T, W2T, W3T, WmT);
  hipLaunchKernelGGL(fps_kernel, dim3(NB), dim3(FTH), 0, stream,
                     vote_xyz, fps_ws, centers, out_xyz, out_indf);
  hipLaunchKernelGGL(ballq_kernel, dim3(NB * NPP), dim3(64), 0, stream,
                     vote_xyz, centers, bidx);
  hipLaunchKernelGGL(mlp_kernel, dim3(NB * NPP), dim3(256), 0, stream,
                     vote_xyz, vote_feat, centers, bidx, W1T, W2T, W3T,
                     sasc, sabi, feat0);
  hipLaunchKernelGGL(head_kernel, dim3(NB * 4), dim3(256), 0, stream,
                     feat0, WmT, bm, msc, mbi, out_feat);
}